// Round 1
// 23693.695 us; speedup vs baseline: 1.2742x; 1.2742x over previous
//
#include <hip/hip_runtime.h>
#include <math.h>

#define H 2048
#define S 8192
#define RPB 8             // hidden rows per block
#define NBLK (H / RPB)    // 256 blocks = 256 CUs
#define PW (H / 2)        // 1024 packed (2-row) words per parity buffer
#define WPT (PW / 256)    // 4 packed words polled per thread

// ---------------------------------------------------------------------------
// GEMM: U[t][j] = sum_k X[t][k] * Wxh[j][k]   (both row-major, NT layout)
// Unchanged from previous round (~1 ms, not the bottleneck).
// ---------------------------------------------------------------------------
__global__ __launch_bounds__(256) void gemm_xw(const float* __restrict__ X,
                                               const float* __restrict__ W,
                                               float* __restrict__ U) {
    __shared__ float As[16][64];   // [k][t]
    __shared__ float Bs[16][64];   // [k][j]
    const int tid = threadIdx.x;
    const int t0 = blockIdx.x * 64;
    const int j0 = blockIdx.y * 64;
    const int tx = tid & 15, ty = tid >> 4;

    float acc[4][4] = {};
    const int lr = tid >> 2;        // 0..63 tile row
    const int lk = (tid & 3) * 4;   // 0,4,8,12 k-offset

    for (int k0 = 0; k0 < H; k0 += 16) {
        float4 a = *(const float4*)&X[(size_t)(t0 + lr) * H + k0 + lk];
        float4 b = *(const float4*)&W[(size_t)(j0 + lr) * H + k0 + lk];
        As[lk + 0][lr] = a.x; As[lk + 1][lr] = a.y; As[lk + 2][lr] = a.z; As[lk + 3][lr] = a.w;
        Bs[lk + 0][lr] = b.x; Bs[lk + 1][lr] = b.y; Bs[lk + 2][lr] = b.z; Bs[lk + 3][lr] = b.w;
        __syncthreads();
#pragma unroll
        for (int kk = 0; kk < 16; ++kk) {
            float4 av = *(const float4*)&As[kk][ty * 4];
            float4 bv = *(const float4*)&Bs[kk][tx * 4];
            float aa[4] = {av.x, av.y, av.z, av.w};
            float bb[4] = {bv.x, bv.y, bv.z, bv.w};
#pragma unroll
            for (int i = 0; i < 4; ++i)
#pragma unroll
                for (int j = 0; j < 4; ++j)
                    acc[i][j] += aa[i] * bb[j];
        }
        __syncthreads();
    }
#pragma unroll
    for (int i = 0; i < 4; ++i) {
        float4 v = {acc[i][0], acc[i][1], acc[i][2], acc[i][3]};
        *(float4*)&U[(size_t)(t0 + ty * 4 + i) * H + j0 + tx * 4] = v;
    }
}

// ---------------------------------------------------------------------------
// Init packed h double-buffer. Each 8B word = 2 fp32 values, each with its
// mantissa LSB replaced by the epoch bit ((t>>1)&1 of the step the value is
// FOR). Parity 0 (used at t=0, epoch 0) gets 0.0f|0 = 0ull  -> h0 = 0 and
// matches immediately. Parity 1 gets epoch bit 1, which mismatches t=1's
// expected epoch 0, so consumers wait for the real publish.
// ---------------------------------------------------------------------------
__global__ void init_ws(unsigned long long* __restrict__ hvt) {
    int i = blockIdx.x * blockDim.x + threadIdx.x;
    if (i < PW) hvt[i] = 0ull;
    else if (i < 2 * PW) hvt[i] = 0x0000000100000001ull;
}

// ---------------------------------------------------------------------------
// Persistent recurrent kernel, pure data-flow sync.
//  - W_hh fragment lives in 64 VGPRs per thread (rows r0..r0+7 x the 8
//    h-columns this thread polls). No W in LDS at all.
//  - Poll loop FMAs each packed h word into 8 per-row partials the moment it
//    arrives, so the matvec runs in the shadow of the broadcast wait; the
//    post-arrival tail is only a 6-stage wave butterfly + 4-wave LDS combine.
//  - Epoch-in-LSB packing: 2 rows per 8B word, every 4B self-describing
//    (tear-safe), half the poll/publish traffic of the tagged scheme.
//    Skew bound (unchanged dataflow argument): publishing step t+2 requires
//    consuming all of t+1, which requires all blocks published t+1, which
//    requires all consumed t -> a slot is overwritten only after everyone
//    read it, and epoch parity disambiguates the 2-step reuse of a slot.
//  - One __syncthreads per step (partials -> combine). Reuse of red[t&1] two
//    steps later is causally safe: any wave's step-t+2 poll completes only
//    after THIS block's wave 0 published t+1, i.e. after its step-t read.
// ---------------------------------------------------------------------------
__global__ __launch_bounds__(256) void rnn_recur(float* __restrict__ out,
                                                 const float* __restrict__ Whh,
                                                 const float* __restrict__ bias,
                                                 unsigned long long* __restrict__ hvt) {
    __shared__ float red[2][RPB][4];   // [parity][row][wave]
    const int tid = threadIdx.x;
    const int r0 = blockIdx.x * RPB;
    const int lane = tid & 63;
    const int wid = tid >> 6;

    // W_hh fragment into registers: wv[j][i] = W[r0+j][2*(i*256+tid) + {0,1}]
    // Per (j,i) a wave reads 512 contiguous bytes -> fully coalesced, once.
    float2 wv[RPB][WPT];
#pragma unroll
    for (int j = 0; j < RPB; ++j)
#pragma unroll
        for (int i = 0; i < WPT; ++i)
            wv[j][i] = *(const float2*)&Whh[(size_t)(r0 + j) * H + 2 * (i * 256 + tid)];

    const float bb = bias[r0 + (tid & 7)];

    for (int t = 0; t < S; ++t) {
        // Prefetch this step's U value (used by wave0 lanes 0..7 only, but an
        // unconditional coalesced load issues early and hides under the poll).
        float u_val = out[(size_t)t * H + r0 + (tid & 7)];

        const unsigned int ep = ((unsigned int)t >> 1) & 1u;
        const unsigned long long* hb = &hvt[(size_t)(t & 1) * PW];
        float acc[RPB] = {};
        unsigned int pend = (1u << WPT) - 1u;
        while (pend) {
            unsigned long long vv[WPT];
#pragma unroll
            for (int i = 0; i < WPT; ++i)
                if (pend & (1u << i))
                    vv[i] = __hip_atomic_load(&hb[i * 256 + tid], __ATOMIC_RELAXED,
                                              __HIP_MEMORY_SCOPE_AGENT);
#pragma unroll
            for (int i = 0; i < WPT; ++i)
                if (pend & (1u << i)) {
                    const unsigned int blo = (unsigned int)vv[i];
                    const unsigned int bhi = (unsigned int)(vv[i] >> 32);
                    if ((((blo ^ ep) | (bhi ^ ep)) & 1u) == 0u) {
                        const float fl = __uint_as_float(blo);
                        const float fh = __uint_as_float(bhi);
#pragma unroll
                        for (int j = 0; j < RPB; ++j)
                            acc[j] += wv[j][i].x * fl + wv[j][i].y * fh;
                        pend &= ~(1u << i);
                    }
                }
            if (pend) __builtin_amdgcn_s_sleep(1);
        }

        // Wave-level butterfly: every lane ends with the wave's total per row.
#pragma unroll
        for (int j = 0; j < RPB; ++j) {
#pragma unroll
            for (int m = 32; m; m >>= 1)
                acc[j] += __shfl_xor(acc[j], m, 64);
        }
        if (lane < RPB) red[t & 1][lane][wid] = acc[lane];
        __syncthreads();

        if (tid < RPB) {
            const float4 r4 = *(const float4*)red[t & 1][tid];
            const float val = tanhf(r4.x + r4.y + r4.z + r4.w + u_val + bb);
            out[(size_t)t * H + r0 + tid] = val;                  // overwrite U with h_t
            if (t == S - 1) out[(size_t)S * H + r0 + tid] = val;  // h_T
            // Pack 2 adjacent rows (+ epoch LSBs) into one 8B publish.
            const float pv = __shfl_xor(val, 1, 64);              // partner row's value
            if ((tid & 1) == 0) {
                const unsigned int e2 = (((unsigned int)(t + 1)) >> 1) & 1u;
                const unsigned long long pk =
                    ((unsigned long long)((__float_as_uint(pv) & ~1u) | e2) << 32) |
                    (unsigned long long)((__float_as_uint(val) & ~1u) | e2);
                __hip_atomic_store(&hvt[(size_t)((t + 1) & 1) * PW + (r0 >> 1) + (tid >> 1)],
                                   pk, __ATOMIC_RELAXED, __HIP_MEMORY_SCOPE_AGENT);
            }
        }
        // No trailing barrier: next step's partials go to red[(t+1)&1], and
        // red[t&1] reuse at t+2 is gated by the global dataflow (see header).
    }
}

extern "C" void kernel_launch(void* const* d_in, const int* in_sizes, int n_in,
                              void* d_out, int out_size, void* d_ws, size_t ws_size,
                              hipStream_t stream) {
    const float* X    = (const float*)d_in[0];  // (8192, 2048)
    const float* Wxh  = (const float*)d_in[1];  // (2048, 2048)
    const float* Whh  = (const float*)d_in[2];  // (2048, 2048)
    const float* bias = (const float*)d_in[3];  // (2048,)
    float* out = (float*)d_out;
    unsigned long long* hvt = (unsigned long long*)d_ws;   // 2*PW packed words (16 KB)

    // Phase 0: init packed h buffer (h0 = 0, epoch 0 / parity-1 poisoned).
    init_ws<<<(2 * PW + 255) / 256, 256, 0, stream>>>(hvt);

    // Phase 1: U = X @ Wxh^T, written into out[0 .. S*H)
    dim3 ggrid(S / 64, H / 64);
    gemm_xw<<<ggrid, 256, 0, stream>>>(X, Wxh, out);

    // Phase 2: sequential recurrence (cooperative launch for co-residency;
    // sync is pure data-flow on epoch-tagged packed h words).
    void* args[] = {(void*)&out, (void*)&Whh, (void*)&bias, (void*)&hvt};
    hipLaunchCooperativeKernel((void*)rnn_recur, dim3(NBLK), dim3(256), args, 0, stream);
}